// Round 9
// baseline (398.987 us; speedup 1.0000x reference)
//
#include <hip/hip_runtime.h>
#include <hip/hip_cooperative_groups.h>

namespace cg = cooperative_groups;

#define NB     32
#define NKEYS  2048
#define D      512
#define GRID   1024
#define NCHUNK 64
#define RPC    (NKEYS / NCHUNK)   // 32 rows per chunk
#define RPB    64                 // rows per block (phase B)
#define RPW    16                 // rows per wave  (phase B)

__device__ __forceinline__ float wave_sum(float v) {
    #pragma unroll
    for (int o = 32; o > 0; o >>= 1) v += __shfl_xor(v, o);
    return v;
}
__device__ __forceinline__ float dot8(float4 a, float4 b, float4 c, float4 d) {
    return a.x * b.x + a.y * b.y + a.z * b.z + a.w * b.w
         + c.x * d.x + c.y * d.y + c.z * d.z + c.w * d.w;
}

// ============ cooperative single-dispatch path ============
__global__ __launch_bounds__(256, 4) void fused_all(
        const float* __restrict__ Q,  const float* __restrict__ K,
        const float* __restrict__ V,  const float* __restrict__ Wk,
        const float* __restrict__ bk, const float* __restrict__ Wq,
        const float* __restrict__ bq, const float* __restrict__ Wh,
        const float* __restrict__ bh,
        float* __restrict__ out, float* __restrict__ wout,
        float* __restrict__ wkh, float* __restrict__ wqh,
        float* __restrict__ cbias, float* __restrict__ p,
        float* __restrict__ partial) {
    cg::grid_group grid = cg::this_grid();
    int tid = threadIdx.x, lane = tid & 63, wv = tid >> 6;
    __shared__ float sred[8];

    // ---- phase A: wkh/wqh (512 blocks), cbias (block 512) ----
    if (blockIdx.x < D) {
        int dk = blockIdx.x;
        float sk = 0.f, sq = 0.f;
        #pragma unroll
        for (int h = tid; h < D; h += 256) {
            float wh = Wh[h];
            sk = fmaf(Wk[dk * D + h], wh, sk);
            sq = fmaf(Wq[dk * D + h], wh, sq);
        }
        sk = wave_sum(sk); sq = wave_sum(sq);
        if (lane == 0) { sred[wv] = sk; sred[wv + 4] = sq; }
        __syncthreads();
        if (tid == 0) wkh[dk] = sred[0] + sred[1] + sred[2] + sred[3];
        if (tid == 1) wqh[dk] = sred[4] + sred[5] + sred[6] + sred[7];
    } else if (blockIdx.x == D) {
        float s = 0.f;
        #pragma unroll
        for (int h = tid; h < D; h += 256) s = fmaf(bk[h] + bq[h], Wh[h], s);
        s = wave_sum(s);
        if (lane == 0) sred[wv] = s;
        __syncthreads();
        if (tid == 0) cbias[0] = sred[0] + sred[1] + sred[2] + sred[3] + bh[0];
    }
    grid.sync();

    // ---- phase B: p = exp(relu(K·wkh + qd)), 64 rows/block ----
    {
        int row0 = blockIdx.x * RPB + wv * RPW;
        int b = row0 >> 11;
        const float4* wr = (const float4*)wkh;
        float4 w0 = wr[lane], w1 = wr[lane + 64];

        const float4* q4  = (const float4*)(Q + b * D);
        const float4* wq4 = (const float4*)wqh;
        float qd = dot8(q4[lane], wq4[lane], q4[lane + 64], wq4[lane + 64]);
        qd = wave_sum(qd) + cbias[0];

        const float4* kr = (const float4*)(K + (long)row0 * D);
        float4 ka = kr[lane], kb = kr[lane + 64];
        #pragma unroll
        for (int r = 0; r < RPW; ++r) {
            float4 na, nb;
            if (r < RPW - 1) {                       // 1-deep prefetch
                na = kr[(r + 1) * (D / 4) + lane];
                nb = kr[(r + 1) * (D / 4) + lane + 64];
            }
            float s = dot8(ka, w0, kb, w1);
            s = wave_sum(s);
            // relu bounds e; exp without max-shift is fp32-safe, cancels in norm
            if (lane == 0) p[row0 + r] = expf(fmaxf(s + qd, 0.f));
            ka = na; kb = nb;
        }
    }
    grid.sync();

    // ---- phase C: unnormalized V partials, 2 chunk-tasks/block ----
    #pragma unroll
    for (int it = 0; it < 2; ++it) {
        int t     = blockIdx.x + it * GRID;          // 0 .. 2047
        int chunk = t & (NCHUNK - 1);
        int b     = t >> 6;
        int n0    = chunk * RPC;
        const float* pb = p + b * NKEYS + n0;
        float pw[RPC];
        #pragma unroll
        for (int r = 0; r < RPC; ++r) pw[r] = pb[r];
        const float2* vb = (const float2*)(V + ((long)b * NKEYS + n0) * D);
        float2 acc = {0.f, 0.f};
        #pragma unroll 8
        for (int r = 0; r < RPC; ++r) {
            float2 vv = vb[r * (D / 2) + tid];
            acc.x = fmaf(pw[r], vv.x, acc.x);
            acc.y = fmaf(pw[r], vv.y, acc.y);
        }
        ((float2*)(partial + (long)t * D))[tid] = acc;
    }
    grid.sync();

    // ---- phase D: finalize (32 blocks) ----
    if (blockIdx.x < NB) {
        int b = blockIdx.x;
        const float4* p4 = (const float4*)(p + b * NKEYS);
        float4 v0 = p4[tid], v1 = p4[tid + 256];
        float s = v0.x + v0.y + v0.z + v0.w + v1.x + v1.y + v1.z + v1.w;
        s = wave_sum(s);
        if (lane == 0) sred[wv] = s;
        __syncthreads();
        float inv = 1.f / (sred[0] + sred[1] + sred[2] + sred[3]);

        float4* wo = (float4*)(wout + b * NKEYS);
        v0.x *= inv; v0.y *= inv; v0.z *= inv; v0.w *= inv;
        v1.x *= inv; v1.y *= inv; v1.z *= inv; v1.w *= inv;
        wo[tid] = v0;
        wo[tid + 256] = v1;

        const float2* yb = (const float2*)(partial + (long)b * NCHUNK * D);
        float2 acc = {0.f, 0.f};
        #pragma unroll
        for (int c = 0; c < NCHUNK; ++c) {
            float2 vv = yb[c * (D / 2) + tid];
            acc.x += vv.x;
            acc.y += vv.y;
        }
        acc.x *= inv; acc.y *= inv;
        ((float2*)(out + b * D))[tid] = acc;
    }
}

// ============ fallback path (R4 structure, proven 57.9 us) ============
__global__ __launch_bounds__(256) void prep_kernel(const float* __restrict__ Wk,
        const float* __restrict__ Wq, const float* __restrict__ Wh,
        const float* __restrict__ bk, const float* __restrict__ bq,
        const float* __restrict__ bh,
        float* __restrict__ wkh, float* __restrict__ wqh, float* __restrict__ cbias) {
    int tid = threadIdx.x, lane = tid & 63, wv = tid >> 6;
    __shared__ float sred[8];
    if (blockIdx.x < D) {
        int dk = blockIdx.x;
        float sk = 0.f, sq = 0.f;
        #pragma unroll
        for (int h = tid; h < D; h += 256) {
            float wh = Wh[h];
            sk = fmaf(Wk[dk * D + h], wh, sk);
            sq = fmaf(Wq[dk * D + h], wh, sq);
        }
        sk = wave_sum(sk); sq = wave_sum(sq);
        if (lane == 0) { sred[wv] = sk; sred[wv + 4] = sq; }
        __syncthreads();
        if (tid == 0) wkh[dk] = sred[0] + sred[1] + sred[2] + sred[3];
        if (tid == 1) wqh[dk] = sred[4] + sred[5] + sred[6] + sred[7];
    } else {
        float s = 0.f;
        #pragma unroll
        for (int h = tid; h < D; h += 256) s = fmaf(bk[h] + bq[h], Wh[h], s);
        s = wave_sum(s);
        if (lane == 0) sred[wv] = s;
        __syncthreads();
        if (tid == 0) cbias[0] = sred[0] + sred[1] + sred[2] + sred[3] + bh[0];
    }
}

__global__ void qdot_kernel(const float* __restrict__ Q, const float* __restrict__ wqh,
                            const float* __restrict__ cbias, float* __restrict__ qdot) {
    int b = blockIdx.x, lane = threadIdx.x;
    const float4* q4 = (const float4*)(Q + b * D);
    const float4* w4 = (const float4*)wqh;
    float s = dot8(q4[lane], w4[lane], q4[lane + 64], w4[lane + 64]);
    s = wave_sum(s);
    if (lane == 0) qdot[b] = s + cbias[0];
}

__global__ __launch_bounds__(256) void energy_kernel(const float* __restrict__ K,
        const float* __restrict__ wkh, const float* __restrict__ qdot,
        float* __restrict__ p) {
    int tid  = threadIdx.x;
    int lane = tid & 63, wv = tid >> 6;
    long row = (long)blockIdx.x * 4 + wv;
    int b = (int)(row >> 11);
    const float4* kr = (const float4*)(K + row * D);
    const float4* wr = (const float4*)wkh;
    float s = dot8(kr[lane], wr[lane], kr[lane + 64], wr[lane + 64]);
    s = wave_sum(s);
    if (lane == 0) p[row] = expf(fmaxf(s + qdot[b], 0.f));
}

__global__ __launch_bounds__(256) void weightedv_kernel(const float* __restrict__ V,
        const float* __restrict__ p, float* __restrict__ partial) {
    int chunk = blockIdx.x & (NCHUNK - 1);
    int b     = blockIdx.x >> 6;
    int tid   = threadIdx.x;
    int n0    = chunk * RPC;
    const float* pb = p + b * NKEYS + n0;
    float pw[RPC];
    #pragma unroll
    for (int r = 0; r < RPC; ++r) pw[r] = pb[r];
    const float2* vb = (const float2*)(V + ((long)b * NKEYS + n0) * D);
    float2 acc = {0.f, 0.f};
    #pragma unroll 8
    for (int r = 0; r < RPC; ++r) {
        float2 vv = vb[r * (D / 2) + tid];
        acc.x = fmaf(pw[r], vv.x, acc.x);
        acc.y = fmaf(pw[r], vv.y, acc.y);
    }
    ((float2*)(partial + (long)blockIdx.x * D))[tid] = acc;
}

__global__ __launch_bounds__(256) void finalize_kernel(const float* __restrict__ p,
        const float* __restrict__ partial, float* __restrict__ out,
        float* __restrict__ wout) {
    int b = blockIdx.x, tid = threadIdx.x;
    int lane = tid & 63, wv = tid >> 6;
    const float4* p4 = (const float4*)(p + b * NKEYS);
    float4 v0 = p4[tid], v1 = p4[tid + 256];
    float s = v0.x + v0.y + v0.z + v0.w + v1.x + v1.y + v1.z + v1.w;
    s = wave_sum(s);
    __shared__ float sred[4];
    if (lane == 0) sred[wv] = s;
    __syncthreads();
    float inv = 1.f / (sred[0] + sred[1] + sred[2] + sred[3]);

    float4* wo = (float4*)(wout + b * NKEYS);
    v0.x *= inv; v0.y *= inv; v0.z *= inv; v0.w *= inv;
    v1.x *= inv; v1.y *= inv; v1.z *= inv; v1.w *= inv;
    wo[tid] = v0;
    wo[tid + 256] = v1;

    const float2* yb = (const float2*)(partial + (long)b * NCHUNK * D);
    float2 acc = {0.f, 0.f};
    #pragma unroll
    for (int c = 0; c < NCHUNK; ++c) {
        float2 vv = yb[c * (D / 2) + tid];
        acc.x += vv.x;
        acc.y += vv.y;
    }
    acc.x *= inv; acc.y *= inv;
    ((float2*)(out + b * D))[tid] = acc;
}

extern "C" void kernel_launch(void* const* d_in, const int* in_sizes, int n_in,
                              void* d_out, int out_size, void* d_ws, size_t ws_size,
                              hipStream_t stream) {
    const float* Q  = (const float*)d_in[0];
    const float* K  = (const float*)d_in[1];
    const float* V  = (const float*)d_in[2];
    const float* Wk = (const float*)d_in[3];
    const float* bk = (const float*)d_in[4];
    const float* Wq = (const float*)d_in[5];
    const float* bq = (const float*)d_in[6];
    const float* Wh = (const float*)d_in[7];
    const float* bh = (const float*)d_in[8];

    float* out  = (float*)d_out;               // [32, 512]
    float* wout = out + NB * D;                // [32, 2048]

    float* ws      = (float*)d_ws;
    float* wkh     = ws;                       // 512
    float* wqh     = ws + 512;                 // 512
    float* cbias   = ws + 1024;                // 1 (pad to 64)
    float* qdot    = ws + 1088;                // 32 (pad to 64)
    float* pbuf    = ws + 1152;                // 65536 (16B aligned)
    float* partial = pbuf + NB * NKEYS;        // 2048*512 = 1048576

    void* args[] = { (void*)&Q, (void*)&K, (void*)&V, (void*)&Wk, (void*)&bk,
                     (void*)&Wq, (void*)&bq, (void*)&Wh, (void*)&bh,
                     (void*)&out, (void*)&wout, (void*)&wkh, (void*)&wqh,
                     (void*)&cbias, (void*)&pbuf, (void*)&partial };
    hipError_t err = hipLaunchCooperativeKernel((void*)fused_all, dim3(GRID),
                                                dim3(256), args, 0, stream);
    if (err != hipSuccess) {
        // deterministic fallback: proven 5-kernel streaming path
        prep_kernel<<<D + 1, 256, 0, stream>>>(Wk, Wq, Wh, bk, bq, bh, wkh, wqh, cbias);
        qdot_kernel<<<NB, 64, 0, stream>>>(Q, wqh, cbias, qdot);
        energy_kernel<<<(NB * NKEYS) / 4, 256, 0, stream>>>(K, wkh, qdot, pbuf);
        weightedv_kernel<<<NB * NCHUNK, 256, 0, stream>>>(V, pbuf, partial);
        finalize_kernel<<<NB, 256, 0, stream>>>(pbuf, partial, out, wout);
    }
}

// Round 10
// 92.624 us; speedup vs baseline: 4.3076x; 4.3076x over previous
//
#include <hip/hip_runtime.h>

#define NB     32
#define NKEYS  2048
#define D      512
#define NCHUNK 64
#define RPC    (NKEYS / NCHUNK)    // 32 rows per chunk

__device__ __forceinline__ float wave_sum(float v) {
    #pragma unroll
    for (int o = 32; o > 0; o >>= 1) v += __shfl_xor(v, o);
    return v;
}
__device__ __forceinline__ float dot8(float4 a, float4 b, float4 c, float4 d) {
    return a.x * b.x + a.y * b.y + a.z * b.z + a.w * b.w
         + c.x * d.x + c.y * d.y + c.z * d.z + c.w * d.w;
}

// blocks 0..511:   wkh[dk] = Wk[dk,:]·Wh
// blocks 512..543: b = blk-512: qdot[b] = sum_h((Q[b]@Wq)[h]+bk[h]+bq[h])·Wh[h] + bh
// Independent halves — no cross-block deps, no atomics.
__global__ __launch_bounds__(256) void prep_kernel(const float* __restrict__ Wk,
        const float* __restrict__ Wq, const float* __restrict__ Wh,
        const float* __restrict__ Q,  const float* __restrict__ bk,
        const float* __restrict__ bq, const float* __restrict__ bh,
        float* __restrict__ wkh, float* __restrict__ qdot) {
    int tid = threadIdx.x, lane = tid & 63, wv = tid >> 6;
    __shared__ float sred[4];
    if (blockIdx.x < D) {
        int dk = blockIdx.x;
        float s = 0.f;
        #pragma unroll
        for (int h = tid; h < D; h += 256) s = fmaf(Wk[dk * D + h], Wh[h], s);
        s = wave_sum(s);
        if (lane == 0) sred[wv] = s;
        __syncthreads();
        if (tid == 0) wkh[dk] = sred[0] + sred[1] + sred[2] + sred[3];
    } else {
        int b = blockIdx.x - D;
        int h0 = tid, h1 = tid + 256;
        float t0 = 0.f, t1 = 0.f;
        #pragma unroll 4
        for (int d = 0; d < D; ++d) {
            float qv = Q[b * D + d];                 // uniform -> scalar load
            t0 = fmaf(qv, Wq[d * D + h0], t0);       // coalesced row reads
            t1 = fmaf(qv, Wq[d * D + h1], t1);
        }
        float acc = (t0 + bk[h0] + bq[h0]) * Wh[h0]
                  + (t1 + bk[h1] + bq[h1]) * Wh[h1];
        acc = wave_sum(acc);
        if (lane == 0) sred[wv] = acc;
        __syncthreads();
        if (tid == 0) qdot[b] = sred[0] + sred[1] + sred[2] + sred[3] + bh[0];
    }
}

// p[b,n] = exp(relu(K[b,n,:]·wkh + qdot[b]))  — one wave per K-row.
// Pure K stream. grid: (NB*NKEYS)/4 = 16384 blocks x 256 threads.
__global__ __launch_bounds__(256) void energy_kernel(const float* __restrict__ K,
        const float* __restrict__ wkh, const float* __restrict__ qdot,
        float* __restrict__ p) {
    int tid  = threadIdx.x;
    int lane = tid & 63, wv = tid >> 6;
    long row = (long)blockIdx.x * 4 + wv;           // 0 .. 65535
    int b = (int)(row >> 11);
    const float4* kr = (const float4*)(K + row * D);
    const float4* wr = (const float4*)wkh;
    float s = dot8(kr[lane], wr[lane], kr[lane + 64], wr[lane + 64]);
    s = wave_sum(s);
    // relu bounds energies; exp without max-shift is fp32-safe and cancels
    // identically after normalization.
    if (lane == 0) p[row] = expf(fmaxf(s + qdot[b], 0.f));
}

// partial[b,chunk,v] = sum_{r} p[b,n0+r] * V[b,n0+r,v]
// p read as uniform scalar loads. Pure V stream, no atomics/fences.
// grid: NB*NCHUNK = 2048 blocks x 256 threads; thread owns v = 2t, 2t+1.
__global__ __launch_bounds__(256) void weightedv_kernel(const float* __restrict__ V,
        const float* __restrict__ p, float* __restrict__ partial) {
    int chunk = blockIdx.x & (NCHUNK - 1);
    int b     = blockIdx.x >> 6;
    int tid   = threadIdx.x;
    int n0    = chunk * RPC;
    const float* pb = p + b * NKEYS + n0;
    float pw[RPC];
    #pragma unroll
    for (int r = 0; r < RPC; ++r) pw[r] = pb[r];    // uniform -> scalar regs
    const float2* vb = (const float2*)(V + ((long)b * NKEYS + n0) * D);
    float2 acc = {0.f, 0.f};
    #pragma unroll 8
    for (int r = 0; r < RPC; ++r) {
        float2 vv = vb[r * (D / 2) + tid];
        acc.x = fmaf(pw[r], vv.x, acc.x);
        acc.y = fmaf(pw[r], vv.y, acc.y);
    }
    ((float2*)(partial + (long)blockIdx.x * D))[tid] = acc;
}

// Per batch: S = sum p; wout = p/S; out = (sum_c partial_c)/S.
// grid: NB blocks x 256 threads
__global__ __launch_bounds__(256) void finalize_kernel(const float* __restrict__ p,
        const float* __restrict__ partial, float* __restrict__ out,
        float* __restrict__ wout) {
    int b = blockIdx.x, tid = threadIdx.x;
    int lane = tid & 63, wv = tid >> 6;

    const float4* p4 = (const float4*)(p + b * NKEYS);
    float4 v0 = p4[tid], v1 = p4[tid + 256];
    float s = v0.x + v0.y + v0.z + v0.w + v1.x + v1.y + v1.z + v1.w;
    s = wave_sum(s);
    __shared__ float sred[4];
    if (lane == 0) sred[wv] = s;
    __syncthreads();
    float inv = 1.f / (sred[0] + sred[1] + sred[2] + sred[3]);

    float4* wo = (float4*)(wout + b * NKEYS);
    v0.x *= inv; v0.y *= inv; v0.z *= inv; v0.w *= inv;
    v1.x *= inv; v1.y *= inv; v1.z *= inv; v1.w *= inv;
    wo[tid] = v0;
    wo[tid + 256] = v1;

    const float2* yb = (const float2*)(partial + (long)b * NCHUNK * D);
    float2 acc = {0.f, 0.f};
    #pragma unroll
    for (int c = 0; c < NCHUNK; ++c) {
        float2 vv = yb[c * (D / 2) + tid];
        acc.x += vv.x;
        acc.y += vv.y;
    }
    acc.x *= inv; acc.y *= inv;
    ((float2*)(out + b * D))[tid] = acc;
}

extern "C" void kernel_launch(void* const* d_in, const int* in_sizes, int n_in,
                              void* d_out, int out_size, void* d_ws, size_t ws_size,
                              hipStream_t stream) {
    const float* Q  = (const float*)d_in[0];
    const float* K  = (const float*)d_in[1];
    const float* V  = (const float*)d_in[2];
    const float* Wk = (const float*)d_in[3];
    const float* bk = (const float*)d_in[4];
    const float* Wq = (const float*)d_in[5];
    const float* bq = (const float*)d_in[6];
    const float* Wh = (const float*)d_in[7];
    const float* bh = (const float*)d_in[8];

    float* out  = (float*)d_out;               // [32, 512]
    float* wout = out + NB * D;                // [32, 2048]

    float* ws      = (float*)d_ws;
    float* wkh     = ws;                       // 512
    float* qdot    = ws + 512;                 // 32 (pad to 128)
    float* pbuf    = ws + 640;                 // 65536 (16B aligned)
    float* partial = pbuf + NB * NKEYS;        // 2048*512 = 1048576

    prep_kernel<<<D + NB, 256, 0, stream>>>(Wk, Wq, Wh, Q, bk, bq, bh, wkh, qdot);
    energy_kernel<<<(NB * NKEYS) / 4, 256, 0, stream>>>(K, wkh, qdot, pbuf);
    weightedv_kernel<<<NB * NCHUNK, 256, 0, stream>>>(V, pbuf, partial);
    finalize_kernel<<<NB, 256, 0, stream>>>(pbuf, partial, out, wout);
}

// Round 11
// 52.894 us; speedup vs baseline: 7.5432x; 1.7511x over previous
//
#include <hip/hip_runtime.h>

#define NB     32
#define NKEYS  2048
#define D      512
#define NSLICE 16                  // v-slices per batch (32 floats each)
#define SLW    (D / NSLICE)        // 32 floats = 8 float4 per slice

__device__ __forceinline__ float wave_sum(float v) {
    #pragma unroll
    for (int o = 32; o > 0; o >>= 1) v += __shfl_xor(v, o);
    return v;
}
__device__ __forceinline__ float dot8(float4 a, float4 b, float4 c, float4 d) {
    return a.x * b.x + a.y * b.y + a.z * b.z + a.w * b.w
         + c.x * d.x + c.y * d.y + c.z * d.z + c.w * d.w;
}

// blocks 0..511: wkh[dk] = Wk[dk,:]·Wh ; wqh[dk] = Wq[dk,:]·Wh
// block 512:     cbias = (bk+bq)·Wh + bh        (all blocks wide-parallel)
__global__ __launch_bounds__(256) void prep_kernel(const float* __restrict__ Wk,
        const float* __restrict__ Wq, const float* __restrict__ Wh,
        const float* __restrict__ bk, const float* __restrict__ bq,
        const float* __restrict__ bh,
        float* __restrict__ wkh, float* __restrict__ wqh, float* __restrict__ cbias) {
    int tid = threadIdx.x, lane = tid & 63, wv = tid >> 6;
    __shared__ float sred[8];
    if (blockIdx.x < D) {
        int dk = blockIdx.x;
        float sk = 0.f, sq = 0.f;
        #pragma unroll
        for (int h = tid; h < D; h += 256) {
            float wh = Wh[h];
            sk = fmaf(Wk[dk * D + h], wh, sk);
            sq = fmaf(Wq[dk * D + h], wh, sq);
        }
        sk = wave_sum(sk); sq = wave_sum(sq);
        if (lane == 0) { sred[wv] = sk; sred[wv + 4] = sq; }
        __syncthreads();
        if (tid == 0) wkh[dk] = sred[0] + sred[1] + sred[2] + sred[3];
        if (tid == 1) wqh[dk] = sred[4] + sred[5] + sred[6] + sred[7];
    } else {
        float s = 0.f;
        #pragma unroll
        for (int h = tid; h < D; h += 256) s = fmaf(bk[h] + bq[h], Wh[h], s);
        s = wave_sum(s);
        if (lane == 0) sred[wv] = s;
        __syncthreads();
        if (tid == 0) cbias[0] = sred[0] + sred[1] + sred[2] + sred[3] + bh[0];
    }
}

// p[b,n] = exp(relu(K[b,n,:]·wkh + qd_b)); qd computed by wave 0 per block
// (blocks never straddle batches: 512 blocks/batch). K loads issue before the
// barrier, so the stream is undisturbed. grid: 16384 blocks x 256 threads.
__global__ __launch_bounds__(256) void energy_kernel(const float* __restrict__ K,
        const float* __restrict__ Q, const float* __restrict__ wkh,
        const float* __restrict__ wqh, const float* __restrict__ cbias,
        float* __restrict__ p) {
    int tid  = threadIdx.x;
    int lane = tid & 63, wv = tid >> 6;
    long row0 = (long)blockIdx.x * 4;
    int b = (int)(row0 >> 11);
    __shared__ float qds;

    // issue this wave's K loads first (independent of the barrier)
    const float4* kr = (const float4*)(K + (row0 + wv) * D);
    const float4* wr = (const float4*)wkh;
    float4 k0 = kr[lane], k1 = kr[lane + 64];
    float4 w0 = wr[lane], w1 = wr[lane + 64];

    if (wv == 0) {                                   // wave 0: qd for batch b
        const float4* q4  = (const float4*)(Q + b * D);
        const float4* wq4 = (const float4*)wqh;
        float qd = dot8(q4[lane], wq4[lane], q4[lane + 64], wq4[lane + 64]);
        qd = wave_sum(qd);
        if (lane == 0) qds = qd + cbias[0];
    }

    float s = dot8(k0, w0, k1, w1);
    s = wave_sum(s);
    __syncthreads();                                 // qds ready
    // relu bounds energies; exp without max-shift is fp32-safe and cancels
    // identically after normalization.
    if (lane == 0) p[row0 + wv] = expf(fmaxf(s + qds, 0.f));
}

// Block (b, slice): S_b from LDS-cached p (8KB, L2-hot), stream V[b,:,slice]
// (128B-granular float4 reads), write FINAL out slice + wout strip.
// No partial buffer, no finalize kernel, no atomics.
// grid: NB*NSLICE = 512 blocks x 256 threads.
__global__ __launch_bounds__(256) void vfinal_kernel(const float* __restrict__ V,
        const float* __restrict__ p, float* __restrict__ out,
        float* __restrict__ wout) {
    int slice = blockIdx.x & (NSLICE - 1);
    int b     = blockIdx.x >> 4;
    int tid   = threadIdx.x, lane = tid & 63, wv = tid >> 6;

    __shared__ float pl[NKEYS];                      // 8 KB
    __shared__ float sredf[4];
    __shared__ float4 red[256];                      // 4 KB

    // load p[b,:] to LDS + block sum
    const float4* p4 = (const float4*)(p + b * NKEYS);
    float4* pl4 = (float4*)pl;
    float s = 0.f;
    #pragma unroll
    for (int i = 0; i < 2; ++i) {
        float4 v = p4[tid + i * 256];
        pl4[tid + i * 256] = v;
        s += v.x + v.y + v.z + v.w;
    }
    s = wave_sum(s);
    if (lane == 0) sredf[wv] = s;
    __syncthreads();
    float inv = 1.f / (sredf[0] + sredf[1] + sredf[2] + sredf[3]);

    // wout strip: 128 weights per block
    int n0 = slice * (NKEYS / NSLICE);
    if (tid < NKEYS / NSLICE) wout[b * NKEYS + n0 + tid] = pl[n0 + tid] * inv;

    // V stream: thread owns float4 v4i of the slice, row-group rg (32 rows/pass)
    int v4i = tid & 7;                               // 0..7
    int rg  = tid >> 3;                              // 0..31
    const float4* vb = (const float4*)(V + (long)b * NKEYS * D);
    int colbase = slice * (SLW / 4);                 // slice*8
    float4 acc = {0.f, 0.f, 0.f, 0.f};
    #pragma unroll 8
    for (int pass = 0; pass < NKEYS / 32; ++pass) {
        int n = pass * 32 + rg;
        float w = pl[n];
        float4 vv = vb[(long)n * (D / 4) + colbase + v4i];
        acc.x = fmaf(w, vv.x, acc.x);
        acc.y = fmaf(w, vv.y, acc.y);
        acc.z = fmaf(w, vv.z, acc.z);
        acc.w = fmaf(w, vv.w, acc.w);
    }

    // combine 32 row-groups per v4 slot
    red[tid] = acc;
    __syncthreads();
    if (tid < 8) {
        float4 a = red[tid];
        #pragma unroll
        for (int g = 1; g < 32; ++g) {
            float4 c = red[g * 8 + tid];
            a.x += c.x; a.y += c.y; a.z += c.z; a.w += c.w;
        }
        a.x *= inv; a.y *= inv; a.z *= inv; a.w *= inv;
        ((float4*)(out + b * D + slice * SLW))[tid] = a;
    }
}

extern "C" void kernel_launch(void* const* d_in, const int* in_sizes, int n_in,
                              void* d_out, int out_size, void* d_ws, size_t ws_size,
                              hipStream_t stream) {
    const float* Q  = (const float*)d_in[0];
    const float* K  = (const float*)d_in[1];
    const float* V  = (const float*)d_in[2];
    const float* Wk = (const float*)d_in[3];
    const float* bk = (const float*)d_in[4];
    const float* Wq = (const float*)d_in[5];
    const float* bq = (const float*)d_in[6];
    const float* Wh = (const float*)d_in[7];
    const float* bh = (const float*)d_in[8];

    float* out  = (float*)d_out;               // [32, 512]
    float* wout = out + NB * D;                // [32, 2048]

    float* ws    = (float*)d_ws;
    float* wkh   = ws;                         // 512
    float* wqh   = ws + 512;                   // 512
    float* cbias = ws + 1024;                  // 1 (pad to 64)
    float* pbuf  = ws + 1088;                  // 65536 (16B aligned)

    prep_kernel<<<D + 1, 256, 0, stream>>>(Wk, Wq, Wh, bk, bq, bh, wkh, wqh, cbias);
    energy_kernel<<<(NB * NKEYS) / 4, 256, 0, stream>>>(K, Q, wkh, wqh, cbias, pbuf);
    vfinal_kernel<<<NB * NSLICE, 256, 0, stream>>>(V, pbuf, out, wout);
}